// Round 6
// baseline (478.279 us; speedup 1.0000x reference)
//
#include <hip/hip_runtime.h>

#define NN 16384
#define FIN 128
#define FH 64
#define FO 32

typedef __attribute__((ext_vector_type(8))) short bf16x8;
typedef __attribute__((ext_vector_type(4))) float f32x4;

__device__ inline unsigned short f2bf(float f) {          // round-to-nearest-even
    unsigned int u = __float_as_uint(f);
    unsigned int r = (u + 0x7FFFu + ((u >> 16) & 1u)) >> 16;
    return (unsigned short)r;
}
__device__ inline float bf2f(unsigned short b) {
    return __uint_as_float((unsigned int)b << 16);
}

// ---------------- CSR build ----------------

__global__ void k_zero(int* __restrict__ cnt) {
    int i = blockIdx.x * 256 + threadIdx.x;
    cnt[i] = 0;
}

__global__ void k_count(const int* __restrict__ dst, int* __restrict__ cnt, int E) {
    int e = blockIdx.x * 256 + threadIdx.x;
    if (e < E) atomicAdd(&cnt[dst[e] & (NN - 1)], 1);
}

__global__ __launch_bounds__(256) void k_scan(const int* __restrict__ cnt,
                                              int* __restrict__ row) {
    __shared__ int part[256];
    __shared__ int off[257];
    int t = threadIdx.x;
    int base = t * 64;
    int s = 0;
    for (int i = 0; i < 64; ++i) s += cnt[base + i];
    part[t] = s;
    __syncthreads();
    if (t == 0) {
        int a = 0;
        for (int i = 0; i < 256; ++i) { off[i] = a; a += part[i]; }
        off[256] = a;
    }
    __syncthreads();
    int a = off[t];
    for (int i = 0; i < 64; ++i) { row[base + i] = a; a += cnt[base + i]; }
    if (t == 0) row[NN] = off[256];
}

__global__ void k_dinv(const int* __restrict__ cnt, float* __restrict__ dinv,
                       int* __restrict__ cur) {
    int i = blockIdx.x * 256 + threadIdx.x;
    dinv[i] = rsqrtf((float)cnt[i] + 1.0f);
    cur[i] = 0;
}

__global__ void k_fill(const int* __restrict__ src, const int* __restrict__ dst,
                       const int* __restrict__ row, int* __restrict__ cur,
                       const float* __restrict__ dinv,
                       int* __restrict__ csr_s, float* __restrict__ csr_w, int E) {
    int e = blockIdx.x * 256 + threadIdx.x;
    if (e >= E) return;
    int s = src[e] & (NN - 1), d = dst[e] & (NN - 1);
    int pos = atomicAdd(&cur[d], 1);
    int slot = row[d] + pos;
    csr_s[slot] = s;
    csr_w[slot] = dinv[s] * dinv[d];
}

// ---------------- dense transforms ----------------

__global__ void k_h0(const float* __restrict__ x, const float* __restrict__ W1,
                     float* __restrict__ h0) {
    int row = blockIdx.x * 4 + (threadIdx.x >> 6);
    int col = threadIdx.x & 63;
    const float* xr = x + row * FIN;
    float acc = 0.f;
#pragma unroll 8
    for (int k = 0; k < FIN; ++k)
        acc = fmaf(xr[k], W1[k * FH + col], acc);
    h0[row * FH + col] = acc;
}

__global__ void k_t(const float* __restrict__ h, const float* __restrict__ Wmu,
                    const float* __restrict__ Wls, float* __restrict__ tmu,
                    float* __restrict__ tls) {
    int row = blockIdx.x * 4 + (threadIdx.x >> 6);
    int l = threadIdx.x & 63;
    const float* hr = h + row * FH;
    const float* W = (l < 32) ? Wmu : Wls;
    int c = l & 31;
    float acc = 0.f;
#pragma unroll 8
    for (int k = 0; k < FH; ++k)
        acc = fmaf(hr[k], W[k * FO + c], acc);
    if (l < 32) tmu[row * FO + c] = acc;
    else        tls[row * FO + c] = acc;
}

// ---------------- gather propagates ----------------

__global__ void k_prop1g(const int* __restrict__ row, const int* __restrict__ csr_s,
                         const float* __restrict__ csr_w, const float* __restrict__ dinv,
                         const float* __restrict__ h0, const float* __restrict__ b1,
                         float* __restrict__ h) {
    int t = blockIdx.x * 256 + threadIdx.x;
    int i = t >> 6, l = t & 63;
    int beg = row[i], end = row[i + 1];
    float di = dinv[i];
    float acc = di * di * h0[i * FH + l];
    for (int j = beg; j < end; ++j) {
        int s = csr_s[j];
        float w = csr_w[j];
        acc = fmaf(w, h0[s * FH + l], acc);
    }
    float v = acc + b1[l];
    h[i * FH + l] = v > 0.f ? v : 0.f;
}

// layer-2 propagate + reparameterize + bf16 hi/lo split of z
__global__ void k_prop2g(const int* __restrict__ row, const int* __restrict__ csr_s,
                         const float* __restrict__ csr_w, const float* __restrict__ dinv,
                         const float* __restrict__ tmu, const float* __restrict__ tls,
                         const float* __restrict__ bmu, const float* __restrict__ bls,
                         const float* __restrict__ eps,
                         float* __restrict__ mu_out, float* __restrict__ ls_out,
                         unsigned short* __restrict__ zh, unsigned short* __restrict__ zl) {
    int t = blockIdx.x * 256 + threadIdx.x;
    int i = t >> 6, l = t & 63;
    int c = l & 31;
    int beg = row[i], end = row[i + 1];
    const float* tp = (l < 32) ? tmu : tls;
    float di = dinv[i];
    float acc = di * di * tp[i * FO + c];
    for (int j = beg; j < end; ++j) {
        int s = csr_s[j];
        float w = csr_w[j];
        acc = fmaf(w, tp[s * FO + c], acc);
    }
    float v = acc + ((l < 32) ? bmu[c] : bls[c]);
    if (l < 32) mu_out[i * FO + c] = v;
    else        ls_out[i * FO + c] = v;
    float other = __shfl_xor(v, 32);   // lane<32 gets ls
    if (l < 32) {
        float zf = fmaf(eps[i * FO + c], __expf(other), v);
        unsigned short hb = f2bf(zf);
        zh[i * FO + c] = hb;
        zl[i * FO + c] = f2bf(zf - bf2f(hb));
    }
}

// ---------------- decode: adj = sigmoid(z @ z^T) via bf16 MFMA hi/lo split ----
// Block = 128x128 output tile, 4 waves; wave w: rows w*32..+31, all 128 cols.
// Gram symmetry: A-frag(row tile t) == B-frag(col tile t) — identical lane layout:
//   lane l holds z[t*16 + (l&15)][(l>>4)*8 .. +8]  (wave load = contiguous 1KB)
// C layout (m89): col = lane&15, row = (lane>>4)*4 + reg.
__global__ __launch_bounds__(256) void k_decode(const unsigned short* __restrict__ zh,
                                                const unsigned short* __restrict__ zl,
                                                float* __restrict__ out) {
    int bi = blockIdx.x & 127, bj = blockIdx.x >> 7;
    int w = threadIdx.x >> 6;
    int l = threadIdx.x & 63;
    int lr = l & 15, lg = l >> 4;

    auto ld = [&](const unsigned short* p, int tile) -> bf16x8 {
        return *(const bf16x8*)(p + ((size_t)tile * 16 + lr) * FO + lg * 8);
    };

    int rt = bi * 8 + w * 2;
    bf16x8 ah0 = ld(zh, rt + 0), al0 = ld(zl, rt + 0);
    bf16x8 ah1 = ld(zh, rt + 1), al1 = ld(zl, rt + 1);

    for (int ct = 0; ct < 8; ++ct) {
        bf16x8 bh = ld(zh, bj * 8 + ct);
        bf16x8 bl = ld(zl, bj * 8 + ct);

        f32x4 a0 = {0.f, 0.f, 0.f, 0.f};
        f32x4 a1 = {0.f, 0.f, 0.f, 0.f};
        a0 = __builtin_amdgcn_mfma_f32_16x16x32_bf16(ah0, bh, a0, 0, 0, 0);
        a0 = __builtin_amdgcn_mfma_f32_16x16x32_bf16(ah0, bl, a0, 0, 0, 0);
        a0 = __builtin_amdgcn_mfma_f32_16x16x32_bf16(al0, bh, a0, 0, 0, 0);
        a1 = __builtin_amdgcn_mfma_f32_16x16x32_bf16(ah1, bh, a1, 0, 0, 0);
        a1 = __builtin_amdgcn_mfma_f32_16x16x32_bf16(ah1, bl, a1, 0, 0, 0);
        a1 = __builtin_amdgcn_mfma_f32_16x16x32_bf16(al1, bh, a1, 0, 0, 0);

        int colg = bj * 128 + ct * 16 + lr;
        size_t base0 = ((size_t)(bi * 128 + w * 32 + lg * 4)) * NN + colg;
        size_t base1 = base0 + (size_t)16 * NN;
#pragma unroll
        for (int r = 0; r < 4; ++r) {
            out[base0 + (size_t)r * NN] = __builtin_amdgcn_rcpf(1.f + __expf(-a0[r]));
            out[base1 + (size_t)r * NN] = __builtin_amdgcn_rcpf(1.f + __expf(-a1[r]));
        }
    }
}

// ---------------- launch ----------------

extern "C" void kernel_launch(void* const* d_in, const int* in_sizes, int n_in,
                              void* d_out, int out_size, void* d_ws, size_t ws_size,
                              hipStream_t stream) {
    const float* x    = (const float*)d_in[0];
    const int*   ei   = (const int*)d_in[1];
    const float* W1   = (const float*)d_in[2];
    const float* b1   = (const float*)d_in[3];
    const float* Wmu  = (const float*)d_in[4];
    const float* bmu  = (const float*)d_in[5];
    const float* Wls  = (const float*)d_in[6];
    const float* bls  = (const float*)d_in[7];
    const float* eps  = (const float*)d_in[8];

    int E = in_sizes[1] / 2;
    const int* src = ei;
    const int* dst = ei + E;

    float* ws = (float*)d_ws;
    float* dinv  = ws;                         // NN f32
    int*   cnt   = (int*)(dinv + NN);          // NN
    int*   row   = cnt + NN;                   // NN+16 (padded for 16B alignment)
    int*   cur   = row + NN + 16;              // NN
    int*   csr_s = cur + NN;                   // E
    float* csr_w = (float*)(csr_s + E);        // E
    float* h0    = csr_w + E;                  // NN*FH
    float* h     = h0 + (size_t)NN * FH;       // NN*FH
    float* tmu   = h  + (size_t)NN * FH;       // NN*FO
    float* tls   = tmu + (size_t)NN * FO;      // NN*FO
    unsigned short* zh = (unsigned short*)(tls + (size_t)NN * FO);  // NN*FO u16
    unsigned short* zl = zh + (size_t)NN * FO;                      // NN*FO u16

    float* adj    = (float*)d_out;
    float* mu_out = adj + (size_t)NN * NN;
    float* ls_out = mu_out + (size_t)NN * FO;

    k_zero<<<NN / 256, 256, 0, stream>>>(cnt);
    k_count<<<(E + 255) / 256, 256, 0, stream>>>(dst, cnt, E);
    k_scan<<<1, 256, 0, stream>>>(cnt, row);
    k_dinv<<<NN / 256, 256, 0, stream>>>(cnt, dinv, cur);
    k_fill<<<(E + 255) / 256, 256, 0, stream>>>(src, dst, row, cur, dinv, csr_s, csr_w, E);
    k_h0<<<NN / 4, 256, 0, stream>>>(x, W1, h0);
    k_prop1g<<<NN * FH / 256, 256, 0, stream>>>(row, csr_s, csr_w, dinv, h0, b1, h);
    k_t<<<NN / 4, 256, 0, stream>>>(h, Wmu, Wls, tmu, tls);
    k_prop2g<<<NN * FH / 256, 256, 0, stream>>>(row, csr_s, csr_w, dinv, tmu, tls,
                                                bmu, bls, eps, mu_out, ls_out, zh, zl);
    k_decode<<<(NN / 128) * (NN / 128), 256, 0, stream>>>(zh, zl, adj);
}

// Round 8
// 373.897 us; speedup vs baseline: 1.2792x; 1.2792x over previous
//
#include <hip/hip_runtime.h>

#define NN 16384
#define FIN 128
#define FH 64
#define FO 32

typedef __attribute__((ext_vector_type(8))) short bf16x8;
typedef __attribute__((ext_vector_type(4))) float f32x4;

__device__ inline unsigned short f2bf(float f) {          // round-to-nearest-even
    unsigned int u = __float_as_uint(f);
    unsigned int r = (u + 0x7FFFu + ((u >> 16) & 1u)) >> 16;
    return (unsigned short)r;
}
__device__ inline float bf2f(unsigned short b) {
    return __uint_as_float((unsigned int)b << 16);
}

// ---------------- CSR build ----------------

__global__ void k_zero(int* __restrict__ cnt) {
    int i = blockIdx.x * 256 + threadIdx.x;
    cnt[i] = 0;
}

__global__ void k_count(const int* __restrict__ dst, int* __restrict__ cnt, int E) {
    int e = blockIdx.x * 256 + threadIdx.x;
    if (e < E) atomicAdd(&cnt[dst[e] & (NN - 1)], 1);
}

__global__ __launch_bounds__(256) void k_scan(const int* __restrict__ cnt,
                                              int* __restrict__ row) {
    __shared__ int part[256];
    __shared__ int off[257];
    int t = threadIdx.x;
    int base = t * 64;
    int s = 0;
    for (int i = 0; i < 64; ++i) s += cnt[base + i];
    part[t] = s;
    __syncthreads();
    if (t == 0) {
        int a = 0;
        for (int i = 0; i < 256; ++i) { off[i] = a; a += part[i]; }
        off[256] = a;
    }
    __syncthreads();
    int a = off[t];
    for (int i = 0; i < 64; ++i) { row[base + i] = a; a += cnt[base + i]; }
    if (t == 0) row[NN] = off[256];
}

__global__ void k_dinv(const int* __restrict__ cnt, float* __restrict__ dinv,
                       int* __restrict__ cur) {
    int i = blockIdx.x * 256 + threadIdx.x;
    dinv[i] = rsqrtf((float)cnt[i] + 1.0f);
    cur[i] = 0;
}

__global__ void k_fill(const int* __restrict__ src, const int* __restrict__ dst,
                       const int* __restrict__ row, int* __restrict__ cur,
                       const float* __restrict__ dinv,
                       int* __restrict__ csr_s, float* __restrict__ csr_w, int E) {
    int e = blockIdx.x * 256 + threadIdx.x;
    if (e >= E) return;
    int s = src[e] & (NN - 1), d = dst[e] & (NN - 1);
    int pos = atomicAdd(&cur[d], 1);
    int slot = row[d] + pos;
    csr_s[slot] = s;
    csr_w[slot] = dinv[s] * dinv[d];
}

// ---------------- dense transforms ----------------

__global__ void k_h0(const float* __restrict__ x, const float* __restrict__ W1,
                     float* __restrict__ h0) {
    int row = blockIdx.x * 4 + (threadIdx.x >> 6);
    int col = threadIdx.x & 63;
    const float* xr = x + row * FIN;
    float acc = 0.f;
#pragma unroll 8
    for (int k = 0; k < FIN; ++k)
        acc = fmaf(xr[k], W1[k * FH + col], acc);
    h0[row * FH + col] = acc;
}

__global__ void k_t(const float* __restrict__ h, const float* __restrict__ Wmu,
                    const float* __restrict__ Wls, float* __restrict__ tmu,
                    float* __restrict__ tls) {
    int row = blockIdx.x * 4 + (threadIdx.x >> 6);
    int l = threadIdx.x & 63;
    const float* hr = h + row * FH;
    const float* W = (l < 32) ? Wmu : Wls;
    int c = l & 31;
    float acc = 0.f;
#pragma unroll 8
    for (int k = 0; k < FH; ++k)
        acc = fmaf(hr[k], W[k * FO + c], acc);
    if (l < 32) tmu[row * FO + c] = acc;
    else        tls[row * FO + c] = acc;
}

// ---------------- gather propagates ----------------

__global__ void k_prop1g(const int* __restrict__ row, const int* __restrict__ csr_s,
                         const float* __restrict__ csr_w, const float* __restrict__ dinv,
                         const float* __restrict__ h0, const float* __restrict__ b1,
                         float* __restrict__ h) {
    int t = blockIdx.x * 256 + threadIdx.x;
    int i = t >> 6, l = t & 63;
    int beg = row[i], end = row[i + 1];
    float di = dinv[i];
    float acc = di * di * h0[i * FH + l];
    for (int j = beg; j < end; ++j) {
        int s = csr_s[j];
        float w = csr_w[j];
        acc = fmaf(w, h0[s * FH + l], acc);
    }
    float v = acc + b1[l];
    h[i * FH + l] = v > 0.f ? v : 0.f;
}

// layer-2 propagate + reparameterize + bf16 hi/lo split of z
__global__ void k_prop2g(const int* __restrict__ row, const int* __restrict__ csr_s,
                         const float* __restrict__ csr_w, const float* __restrict__ dinv,
                         const float* __restrict__ tmu, const float* __restrict__ tls,
                         const float* __restrict__ bmu, const float* __restrict__ bls,
                         const float* __restrict__ eps,
                         float* __restrict__ mu_out, float* __restrict__ ls_out,
                         unsigned short* __restrict__ zh, unsigned short* __restrict__ zl) {
    int t = blockIdx.x * 256 + threadIdx.x;
    int i = t >> 6, l = t & 63;
    int c = l & 31;
    int beg = row[i], end = row[i + 1];
    const float* tp = (l < 32) ? tmu : tls;
    float di = dinv[i];
    float acc = di * di * tp[i * FO + c];
    for (int j = beg; j < end; ++j) {
        int s = csr_s[j];
        float w = csr_w[j];
        acc = fmaf(w, tp[s * FO + c], acc);
    }
    float v = acc + ((l < 32) ? bmu[c] : bls[c]);
    if (l < 32) mu_out[i * FO + c] = v;
    else        ls_out[i * FO + c] = v;
    float other = __shfl_xor(v, 32);   // lane<32 gets ls
    if (l < 32) {
        float zf = fmaf(eps[i * FO + c], __expf(other), v);
        unsigned short hb = f2bf(zf);
        zh[i * FO + c] = hb;
        zl[i * FO + c] = f2bf(zf - bf2f(hb));
    }
}

// ---------------- decode: adj = sigmoid(z @ z^T), MFMA + LDS-staged stores ----
// Swapped operands: D = mfma(ct_frag, row_frag) -> lane l, reg r holds
//   S[rowtile*16 + (l&15)][cttile*16 + (l>>4)*4 + r]   (4 consecutive COLS/lane)
// -> sigmoid -> ds_write_b128 into tile[128][132] -> barrier ->
// stream out row-major float4 (4 x 256B segments per wave store instruction).
__global__ __launch_bounds__(256) void k_decode(const unsigned short* __restrict__ zh,
                                                const unsigned short* __restrict__ zl,
                                                float* __restrict__ out) {
    __shared__ float tile[128][132];   // pad 132: 4-row stride -> bank+16, conflict-free
    int bi = blockIdx.x & 127, bj = blockIdx.x >> 7;
    int w = threadIdx.x >> 6;
    int l = threadIdx.x & 63;
    int lr = l & 15, lg = l >> 4;

    auto ld = [&](const unsigned short* p, int t) -> bf16x8 {
        return *(const bf16x8*)(p + ((size_t)t * 16 + lr) * FO + lg * 8);
    };

    int rt = bi * 8 + w * 2;
    bf16x8 rh0 = ld(zh, rt + 0), rl0 = ld(zl, rt + 0);
    bf16x8 rh1 = ld(zh, rt + 1), rl1 = ld(zl, rt + 1);

    for (int ct = 0; ct < 8; ++ct) {
        bf16x8 ch = ld(zh, bj * 8 + ct);
        bf16x8 cl = ld(zl, bj * 8 + ct);

        f32x4 a0 = {0.f, 0.f, 0.f, 0.f};
        f32x4 a1 = {0.f, 0.f, 0.f, 0.f};
        a0 = __builtin_amdgcn_mfma_f32_16x16x32_bf16(ch, rh0, a0, 0, 0, 0);
        a0 = __builtin_amdgcn_mfma_f32_16x16x32_bf16(ch, rl0, a0, 0, 0, 0);
        a0 = __builtin_amdgcn_mfma_f32_16x16x32_bf16(cl, rh0, a0, 0, 0, 0);
        a1 = __builtin_amdgcn_mfma_f32_16x16x32_bf16(ch, rh1, a1, 0, 0, 0);
        a1 = __builtin_amdgcn_mfma_f32_16x16x32_bf16(ch, rl1, a1, 0, 0, 0);
        a1 = __builtin_amdgcn_mfma_f32_16x16x32_bf16(cl, rh1, a1, 0, 0, 0);

        float4 v0, v1;
        v0.x = __builtin_amdgcn_rcpf(1.f + __expf(-a0[0]));
        v0.y = __builtin_amdgcn_rcpf(1.f + __expf(-a0[1]));
        v0.z = __builtin_amdgcn_rcpf(1.f + __expf(-a0[2]));
        v0.w = __builtin_amdgcn_rcpf(1.f + __expf(-a0[3]));
        v1.x = __builtin_amdgcn_rcpf(1.f + __expf(-a1[0]));
        v1.y = __builtin_amdgcn_rcpf(1.f + __expf(-a1[1]));
        v1.z = __builtin_amdgcn_rcpf(1.f + __expf(-a1[2]));
        v1.w = __builtin_amdgcn_rcpf(1.f + __expf(-a1[3]));

        int col = ct * 16 + lg * 4;
        *(float4*)&tile[w * 32 + lr][col]      = v0;
        *(float4*)&tile[w * 32 + 16 + lr][col] = v1;
    }
    __syncthreads();

    int tx = threadIdx.x & 15, ty = threadIdx.x >> 4;
#pragma unroll
    for (int i = 0; i < 8; ++i) {
        int r = ty * 8 + i;
        size_t rowoff = ((size_t)(bi * 128 + r)) * NN + bj * 128;
#pragma unroll
        for (int cb = 0; cb < 2; ++cb)
            *(float4*)(out + rowoff + cb * 64 + tx * 4) =
                *(const float4*)&tile[r][cb * 64 + tx * 4];
    }
}

// ---------------- launch ----------------

extern "C" void kernel_launch(void* const* d_in, const int* in_sizes, int n_in,
                              void* d_out, int out_size, void* d_ws, size_t ws_size,
                              hipStream_t stream) {
    const float* x    = (const float*)d_in[0];
    const int*   ei   = (const int*)d_in[1];
    const float* W1   = (const float*)d_in[2];
    const float* b1   = (const float*)d_in[3];
    const float* Wmu  = (const float*)d_in[4];
    const float* bmu  = (const float*)d_in[5];
    const float* Wls  = (const float*)d_in[6];
    const float* bls  = (const float*)d_in[7];
    const float* eps  = (const float*)d_in[8];

    int E = in_sizes[1] / 2;
    const int* src = ei;
    const int* dst = ei + E;

    float* ws = (float*)d_ws;
    float* dinv  = ws;                         // NN f32
    int*   cnt   = (int*)(dinv + NN);          // NN
    int*   row   = cnt + NN;                   // NN+16
    int*   cur   = row + NN + 16;              // NN
    int*   csr_s = cur + NN;                   // E
    float* csr_w = (float*)(csr_s + E);        // E
    float* h0    = csr_w + E;                  // NN*FH
    float* h     = h0 + (size_t)NN * FH;       // NN*FH
    float* tmu   = h  + (size_t)NN * FH;       // NN*FO
    float* tls   = tmu + (size_t)NN * FO;      // NN*FO
    unsigned short* zh = (unsigned short*)(tls + (size_t)NN * FO);  // NN*FO u16
    unsigned short* zl = zh + (size_t)NN * FO;                      // NN*FO u16

    float* adj    = (float*)d_out;
    float* mu_out = adj + (size_t)NN * NN;
    float* ls_out = mu_out + (size_t)NN * FO;

    k_zero<<<NN / 256, 256, 0, stream>>>(cnt);
    k_count<<<(E + 255) / 256, 256, 0, stream>>>(dst, cnt, E);
    k_scan<<<1, 256, 0, stream>>>(cnt, row);
    k_dinv<<<NN / 256, 256, 0, stream>>>(cnt, dinv, cur);
    k_fill<<<(E + 255) / 256, 256, 0, stream>>>(src, dst, row, cur, dinv, csr_s, csr_w, E);
    k_h0<<<NN / 4, 256, 0, stream>>>(x, W1, h0);
    k_prop1g<<<NN * FH / 256, 256, 0, stream>>>(row, csr_s, csr_w, dinv, h0, b1, h);
    k_t<<<NN / 4, 256, 0, stream>>>(h, Wmu, Wls, tmu, tls);
    k_prop2g<<<NN * FH / 256, 256, 0, stream>>>(row, csr_s, csr_w, dinv, tmu, tls,
                                                bmu, bls, eps, mu_out, ls_out, zh, zl);
    k_decode<<<(NN / 128) * (NN / 128), 256, 0, stream>>>(zh, zl, adj);
}

// Round 9
// 340.385 us; speedup vs baseline: 1.4051x; 1.0985x over previous
//
#include <hip/hip_runtime.h>

#define NN 16384
#define FIN 128
#define FH 64
#define FO 32

typedef __attribute__((ext_vector_type(8))) short bf16x8;
typedef __attribute__((ext_vector_type(4))) float f32x4;

__device__ inline unsigned short f2bf(float f) {          // round-to-nearest-even
    unsigned int u = __float_as_uint(f);
    unsigned int r = (u + 0x7FFFu + ((u >> 16) & 1u)) >> 16;
    return (unsigned short)r;
}
__device__ inline float bf2f(unsigned short b) {
    return __uint_as_float((unsigned int)b << 16);
}

// ---------------- CSR build ----------------

__global__ void k_zero(int* __restrict__ cnt) {
    int i = blockIdx.x * 256 + threadIdx.x;
    cnt[i] = 0;
}

__global__ void k_count(const int* __restrict__ dst, int* __restrict__ cnt, int E) {
    int e = blockIdx.x * 256 + threadIdx.x;
    if (e < E) atomicAdd(&cnt[dst[e] & (NN - 1)], 1);
}

__global__ __launch_bounds__(256) void k_scan(const int* __restrict__ cnt,
                                              int* __restrict__ row) {
    __shared__ int part[256];
    __shared__ int off[257];
    int t = threadIdx.x;
    int base = t * 64;
    int s = 0;
    for (int i = 0; i < 64; ++i) s += cnt[base + i];
    part[t] = s;
    __syncthreads();
    if (t == 0) {
        int a = 0;
        for (int i = 0; i < 256; ++i) { off[i] = a; a += part[i]; }
        off[256] = a;
    }
    __syncthreads();
    int a = off[t];
    for (int i = 0; i < 64; ++i) { row[base + i] = a; a += cnt[base + i]; }
    if (t == 0) row[NN] = off[256];
}

__global__ void k_dinv(const int* __restrict__ cnt, float* __restrict__ dinv,
                       int* __restrict__ cur) {
    int i = blockIdx.x * 256 + threadIdx.x;
    dinv[i] = rsqrtf((float)cnt[i] + 1.0f);
    cur[i] = 0;
}

__global__ void k_fill(const int* __restrict__ src, const int* __restrict__ dst,
                       const int* __restrict__ row, int* __restrict__ cur,
                       const float* __restrict__ dinv,
                       int* __restrict__ csr_s, float* __restrict__ csr_w, int E) {
    int e = blockIdx.x * 256 + threadIdx.x;
    if (e >= E) return;
    int s = src[e] & (NN - 1), d = dst[e] & (NN - 1);
    int pos = atomicAdd(&cur[d], 1);
    int slot = row[d] + pos;
    csr_s[slot] = s;
    csr_w[slot] = dinv[s] * dinv[d];
}

// ---------------- dense transforms ----------------

__global__ void k_h0(const float* __restrict__ x, const float* __restrict__ W1,
                     float* __restrict__ h0) {
    int row = blockIdx.x * 4 + (threadIdx.x >> 6);
    int col = threadIdx.x & 63;
    const float* xr = x + row * FIN;
    float acc = 0.f;
#pragma unroll 8
    for (int k = 0; k < FIN; ++k)
        acc = fmaf(xr[k], W1[k * FH + col], acc);
    h0[row * FH + col] = acc;
}

__global__ void k_t(const float* __restrict__ h, const float* __restrict__ Wmu,
                    const float* __restrict__ Wls, float* __restrict__ tmu,
                    float* __restrict__ tls) {
    int row = blockIdx.x * 4 + (threadIdx.x >> 6);
    int l = threadIdx.x & 63;
    const float* hr = h + row * FH;
    const float* W = (l < 32) ? Wmu : Wls;
    int c = l & 31;
    float acc = 0.f;
#pragma unroll 8
    for (int k = 0; k < FH; ++k)
        acc = fmaf(hr[k], W[k * FO + c], acc);
    if (l < 32) tmu[row * FO + c] = acc;
    else        tls[row * FO + c] = acc;
}

// ---------------- gather propagates ----------------

__global__ void k_prop1g(const int* __restrict__ row, const int* __restrict__ csr_s,
                         const float* __restrict__ csr_w, const float* __restrict__ dinv,
                         const float* __restrict__ h0, const float* __restrict__ b1,
                         float* __restrict__ h) {
    int t = blockIdx.x * 256 + threadIdx.x;
    int i = t >> 6, l = t & 63;
    int beg = row[i], end = row[i + 1];
    float di = dinv[i];
    float acc = di * di * h0[i * FH + l];
    for (int j = beg; j < end; ++j) {
        int s = csr_s[j];
        float w = csr_w[j];
        acc = fmaf(w, h0[s * FH + l], acc);
    }
    float v = acc + b1[l];
    h[i * FH + l] = v > 0.f ? v : 0.f;
}

// layer-2 propagate + reparameterize + bf16 hi/lo split of z
__global__ void k_prop2g(const int* __restrict__ row, const int* __restrict__ csr_s,
                         const float* __restrict__ csr_w, const float* __restrict__ dinv,
                         const float* __restrict__ tmu, const float* __restrict__ tls,
                         const float* __restrict__ bmu, const float* __restrict__ bls,
                         const float* __restrict__ eps,
                         float* __restrict__ mu_out, float* __restrict__ ls_out,
                         unsigned short* __restrict__ zh, unsigned short* __restrict__ zl) {
    int t = blockIdx.x * 256 + threadIdx.x;
    int i = t >> 6, l = t & 63;
    int c = l & 31;
    int beg = row[i], end = row[i + 1];
    const float* tp = (l < 32) ? tmu : tls;
    float di = dinv[i];
    float acc = di * di * tp[i * FO + c];
    for (int j = beg; j < end; ++j) {
        int s = csr_s[j];
        float w = csr_w[j];
        acc = fmaf(w, tp[s * FO + c], acc);
    }
    float v = acc + ((l < 32) ? bmu[c] : bls[c]);
    if (l < 32) mu_out[i * FO + c] = v;
    else        ls_out[i * FO + c] = v;
    float other = __shfl_xor(v, 32);   // lane<32 gets ls
    if (l < 32) {
        float zf = fmaf(eps[i * FO + c], __expf(other), v);
        unsigned short hb = f2bf(zf);
        zh[i * FO + c] = hb;
        zl[i * FO + c] = f2bf(zf - bf2f(hb));
    }
}

// ---------------- decode: adj = sigmoid(z @ z^T), MFMA + LDS-staged stores ----
// bj-FAST block ordering: consecutive blocks fill consecutive column strips of
// the same 128-row band -> concurrent blocks write a dense contiguous ~8MB
// region (DRAM page locality), instead of 512B chunks scattered over 1GB.
__global__ __launch_bounds__(256) void k_decode(const unsigned short* __restrict__ zh,
                                                const unsigned short* __restrict__ zl,
                                                float* __restrict__ out) {
    __shared__ float tile[128][132];   // pad 132: 4-row stride -> bank+16, conflict-free
    int bj = blockIdx.x & 127, bi = blockIdx.x >> 7;   // bj fast!
    int w = threadIdx.x >> 6;
    int l = threadIdx.x & 63;
    int lr = l & 15, lg = l >> 4;

    auto ld = [&](const unsigned short* p, int t) -> bf16x8 {
        return *(const bf16x8*)(p + ((size_t)t * 16 + lr) * FO + lg * 8);
    };

    int rt = bi * 8 + w * 2;
    bf16x8 rh0 = ld(zh, rt + 0), rl0 = ld(zl, rt + 0);
    bf16x8 rh1 = ld(zh, rt + 1), rl1 = ld(zl, rt + 1);

    for (int ct = 0; ct < 8; ++ct) {
        bf16x8 ch = ld(zh, bj * 8 + ct);
        bf16x8 cl = ld(zl, bj * 8 + ct);

        f32x4 a0 = {0.f, 0.f, 0.f, 0.f};
        f32x4 a1 = {0.f, 0.f, 0.f, 0.f};
        a0 = __builtin_amdgcn_mfma_f32_16x16x32_bf16(ch, rh0, a0, 0, 0, 0);
        a0 = __builtin_amdgcn_mfma_f32_16x16x32_bf16(ch, rl0, a0, 0, 0, 0);
        a0 = __builtin_amdgcn_mfma_f32_16x16x32_bf16(cl, rh0, a0, 0, 0, 0);
        a1 = __builtin_amdgcn_mfma_f32_16x16x32_bf16(ch, rh1, a1, 0, 0, 0);
        a1 = __builtin_amdgcn_mfma_f32_16x16x32_bf16(ch, rl1, a1, 0, 0, 0);
        a1 = __builtin_amdgcn_mfma_f32_16x16x32_bf16(cl, rh1, a1, 0, 0, 0);

        float4 v0, v1;
        v0.x = __builtin_amdgcn_rcpf(1.f + __expf(-a0[0]));
        v0.y = __builtin_amdgcn_rcpf(1.f + __expf(-a0[1]));
        v0.z = __builtin_amdgcn_rcpf(1.f + __expf(-a0[2]));
        v0.w = __builtin_amdgcn_rcpf(1.f + __expf(-a0[3]));
        v1.x = __builtin_amdgcn_rcpf(1.f + __expf(-a1[0]));
        v1.y = __builtin_amdgcn_rcpf(1.f + __expf(-a1[1]));
        v1.z = __builtin_amdgcn_rcpf(1.f + __expf(-a1[2]));
        v1.w = __builtin_amdgcn_rcpf(1.f + __expf(-a1[3]));

        int col = ct * 16 + lg * 4;
        *(float4*)&tile[w * 32 + lr][col]      = v0;
        *(float4*)&tile[w * 32 + 16 + lr][col] = v1;
    }
    __syncthreads();

    int tx = threadIdx.x & 15, ty = threadIdx.x >> 4;
#pragma unroll
    for (int i = 0; i < 8; ++i) {
        int r = ty * 8 + i;
        size_t rowoff = ((size_t)(bi * 128 + r)) * NN + bj * 128;
#pragma unroll
        for (int cb = 0; cb < 2; ++cb)
            *(float4*)(out + rowoff + cb * 64 + tx * 4) =
                *(const float4*)&tile[r][cb * 64 + tx * 4];
    }
}

// ---------------- launch ----------------

extern "C" void kernel_launch(void* const* d_in, const int* in_sizes, int n_in,
                              void* d_out, int out_size, void* d_ws, size_t ws_size,
                              hipStream_t stream) {
    const float* x    = (const float*)d_in[0];
    const int*   ei   = (const int*)d_in[1];
    const float* W1   = (const float*)d_in[2];
    const float* b1   = (const float*)d_in[3];
    const float* Wmu  = (const float*)d_in[4];
    const float* bmu  = (const float*)d_in[5];
    const float* Wls  = (const float*)d_in[6];
    const float* bls  = (const float*)d_in[7];
    const float* eps  = (const float*)d_in[8];

    int E = in_sizes[1] / 2;
    const int* src = ei;
    const int* dst = ei + E;

    float* ws = (float*)d_ws;
    float* dinv  = ws;                         // NN f32
    int*   cnt   = (int*)(dinv + NN);          // NN
    int*   row   = cnt + NN;                   // NN+16
    int*   cur   = row + NN + 16;              // NN
    int*   csr_s = cur + NN;                   // E
    float* csr_w = (float*)(csr_s + E);        // E
    float* h0    = csr_w + E;                  // NN*FH
    float* h     = h0 + (size_t)NN * FH;       // NN*FH
    float* tmu   = h  + (size_t)NN * FH;       // NN*FO
    float* tls   = tmu + (size_t)NN * FO;      // NN*FO
    unsigned short* zh = (unsigned short*)(tls + (size_t)NN * FO);  // NN*FO u16
    unsigned short* zl = zh + (size_t)NN * FO;                      // NN*FO u16

    float* adj    = (float*)d_out;
    float* mu_out = adj + (size_t)NN * NN;
    float* ls_out = mu_out + (size_t)NN * FO;

    k_zero<<<NN / 256, 256, 0, stream>>>(cnt);
    k_count<<<(E + 255) / 256, 256, 0, stream>>>(dst, cnt, E);
    k_scan<<<1, 256, 0, stream>>>(cnt, row);
    k_dinv<<<NN / 256, 256, 0, stream>>>(cnt, dinv, cur);
    k_fill<<<(E + 255) / 256, 256, 0, stream>>>(src, dst, row, cur, dinv, csr_s, csr_w, E);
    k_h0<<<NN / 4, 256, 0, stream>>>(x, W1, h0);
    k_prop1g<<<NN * FH / 256, 256, 0, stream>>>(row, csr_s, csr_w, dinv, h0, b1, h);
    k_t<<<NN / 4, 256, 0, stream>>>(h, Wmu, Wls, tmu, tls);
    k_prop2g<<<NN * FH / 256, 256, 0, stream>>>(row, csr_s, csr_w, dinv, tmu, tls,
                                                bmu, bls, eps, mu_out, ls_out, zh, zl);
    k_decode<<<(NN / 128) * (NN / 128), 256, 0, stream>>>(zh, zl, adj);
}

// Round 10
// 336.026 us; speedup vs baseline: 1.4233x; 1.0130x over previous
//
#include <hip/hip_runtime.h>

#define NN 16384
#define FIN 128
#define FH 64
#define FO 32

typedef __attribute__((ext_vector_type(8))) short bf16x8;
typedef __attribute__((ext_vector_type(4))) float f32x4;

__device__ inline unsigned short f2bf(float f) {          // round-to-nearest-even
    unsigned int u = __float_as_uint(f);
    unsigned int r = (u + 0x7FFFu + ((u >> 16) & 1u)) >> 16;
    return (unsigned short)r;
}
__device__ inline float bf2f(unsigned short b) {
    return __uint_as_float((unsigned int)b << 16);
}

// ---------------- CSR build ----------------

__global__ void k_zero(int* __restrict__ cnt) {
    int i = blockIdx.x * 256 + threadIdx.x;
    cnt[i] = 0;
}

__global__ void k_count(const int* __restrict__ dst, int* __restrict__ cnt, int E) {
    int e = blockIdx.x * 256 + threadIdx.x;
    if (e < E) atomicAdd(&cnt[dst[e] & (NN - 1)], 1);
}

__global__ __launch_bounds__(256) void k_scan(const int* __restrict__ cnt,
                                              int* __restrict__ row) {
    __shared__ int part[256];
    __shared__ int off[257];
    int t = threadIdx.x;
    int base = t * 64;
    int s = 0;
    for (int i = 0; i < 64; ++i) s += cnt[base + i];
    part[t] = s;
    __syncthreads();
    if (t == 0) {
        int a = 0;
        for (int i = 0; i < 256; ++i) { off[i] = a; a += part[i]; }
        off[256] = a;
    }
    __syncthreads();
    int a = off[t];
    for (int i = 0; i < 64; ++i) { row[base + i] = a; a += cnt[base + i]; }
    if (t == 0) row[NN] = off[256];
}

__global__ void k_dinv(const int* __restrict__ cnt, float* __restrict__ dinv,
                       int* __restrict__ cur) {
    int i = blockIdx.x * 256 + threadIdx.x;
    dinv[i] = rsqrtf((float)cnt[i] + 1.0f);
    cur[i] = 0;
}

__global__ void k_fill(const int* __restrict__ src, const int* __restrict__ dst,
                       const int* __restrict__ row, int* __restrict__ cur,
                       const float* __restrict__ dinv,
                       int* __restrict__ csr_s, float* __restrict__ csr_w, int E) {
    int e = blockIdx.x * 256 + threadIdx.x;
    if (e >= E) return;
    int s = src[e] & (NN - 1), d = dst[e] & (NN - 1);
    int pos = atomicAdd(&cur[d], 1);
    int slot = row[d] + pos;
    csr_s[slot] = s;
    csr_w[slot] = dinv[s] * dinv[d];
}

// ---------------- dense transforms ----------------

__global__ void k_h0(const float* __restrict__ x, const float* __restrict__ W1,
                     float* __restrict__ h0) {
    int row = blockIdx.x * 4 + (threadIdx.x >> 6);
    int col = threadIdx.x & 63;
    const float* xr = x + row * FIN;
    float acc = 0.f;
#pragma unroll 8
    for (int k = 0; k < FIN; ++k)
        acc = fmaf(xr[k], W1[k * FH + col], acc);
    h0[row * FH + col] = acc;
}

__global__ void k_t(const float* __restrict__ h, const float* __restrict__ Wmu,
                    const float* __restrict__ Wls, float* __restrict__ tmu,
                    float* __restrict__ tls) {
    int row = blockIdx.x * 4 + (threadIdx.x >> 6);
    int l = threadIdx.x & 63;
    const float* hr = h + row * FH;
    const float* W = (l < 32) ? Wmu : Wls;
    int c = l & 31;
    float acc = 0.f;
#pragma unroll 8
    for (int k = 0; k < FH; ++k)
        acc = fmaf(hr[k], W[k * FO + c], acc);
    if (l < 32) tmu[row * FO + c] = acc;
    else        tls[row * FO + c] = acc;
}

// ---------------- gather propagates ----------------

__global__ void k_prop1g(const int* __restrict__ row, const int* __restrict__ csr_s,
                         const float* __restrict__ csr_w, const float* __restrict__ dinv,
                         const float* __restrict__ h0, const float* __restrict__ b1,
                         float* __restrict__ h) {
    int t = blockIdx.x * 256 + threadIdx.x;
    int i = t >> 6, l = t & 63;
    int beg = row[i], end = row[i + 1];
    float di = dinv[i];
    float acc = di * di * h0[i * FH + l];
    for (int j = beg; j < end; ++j) {
        int s = csr_s[j];
        float w = csr_w[j];
        acc = fmaf(w, h0[s * FH + l], acc);
    }
    float v = acc + b1[l];
    h[i * FH + l] = v > 0.f ? v : 0.f;
}

// layer-2 propagate + reparameterize + bf16 hi/lo split of z
__global__ void k_prop2g(const int* __restrict__ row, const int* __restrict__ csr_s,
                         const float* __restrict__ csr_w, const float* __restrict__ dinv,
                         const float* __restrict__ tmu, const float* __restrict__ tls,
                         const float* __restrict__ bmu, const float* __restrict__ bls,
                         const float* __restrict__ eps,
                         float* __restrict__ mu_out, float* __restrict__ ls_out,
                         unsigned short* __restrict__ zh, unsigned short* __restrict__ zl) {
    int t = blockIdx.x * 256 + threadIdx.x;
    int i = t >> 6, l = t & 63;
    int c = l & 31;
    int beg = row[i], end = row[i + 1];
    const float* tp = (l < 32) ? tmu : tls;
    float di = dinv[i];
    float acc = di * di * tp[i * FO + c];
    for (int j = beg; j < end; ++j) {
        int s = csr_s[j];
        float w = csr_w[j];
        acc = fmaf(w, tp[s * FO + c], acc);
    }
    float v = acc + ((l < 32) ? bmu[c] : bls[c]);
    if (l < 32) mu_out[i * FO + c] = v;
    else        ls_out[i * FO + c] = v;
    float other = __shfl_xor(v, 32);   // lane<32 gets ls
    if (l < 32) {
        float zf = fmaf(eps[i * FO + c], __expf(other), v);
        unsigned short hb = f2bf(zf);
        zh[i * FO + c] = hb;
        zl[i * FO + c] = f2bf(zf - bf2f(hb));
    }
}

// ---------------- decode: adj = sigmoid(z @ z^T) ----------------
// MFMA + per-wave private LDS slab, NO barriers: each wave computes and then
// streams out its own 32 rows; waves free-run and stagger so stores issue
// continuously. bj-fast block order for DRAM page locality. ct-frag loads
// hoisted so they pipeline (vmcnt), ct loop fully unrolled.
__global__ __launch_bounds__(256) void k_decode(const unsigned short* __restrict__ zh,
                                                const unsigned short* __restrict__ zl,
                                                float* __restrict__ out) {
    __shared__ float slab[4][32][132];   // per-wave private; 67.6 KB -> 2 blocks/CU
    int bj = blockIdx.x & 127, bi = blockIdx.x >> 7;   // bj fast
    int w = threadIdx.x >> 6;
    int l = threadIdx.x & 63;
    int lr = l & 15, lg = l >> 4;

    auto ld = [&](const unsigned short* p, int t) -> bf16x8 {
        return *(const bf16x8*)(p + ((size_t)t * 16 + lr) * FO + lg * 8);
    };

    int rt = bi * 8 + w * 2;
    bf16x8 rh0 = ld(zh, rt + 0), rl0 = ld(zl, rt + 0);
    bf16x8 rh1 = ld(zh, rt + 1), rl1 = ld(zl, rt + 1);

    bf16x8 ch[8], cl[8];
#pragma unroll
    for (int ct = 0; ct < 8; ++ct) {
        ch[ct] = ld(zh, bj * 8 + ct);
        cl[ct] = ld(zl, bj * 8 + ct);
    }

#pragma unroll
    for (int ct = 0; ct < 8; ++ct) {
        f32x4 a0 = {0.f, 0.f, 0.f, 0.f};
        f32x4 a1 = {0.f, 0.f, 0.f, 0.f};
        a0 = __builtin_amdgcn_mfma_f32_16x16x32_bf16(ch[ct], rh0, a0, 0, 0, 0);
        a0 = __builtin_amdgcn_mfma_f32_16x16x32_bf16(ch[ct], rl0, a0, 0, 0, 0);
        a0 = __builtin_amdgcn_mfma_f32_16x16x32_bf16(cl[ct], rh0, a0, 0, 0, 0);
        a1 = __builtin_amdgcn_mfma_f32_16x16x32_bf16(ch[ct], rh1, a1, 0, 0, 0);
        a1 = __builtin_amdgcn_mfma_f32_16x16x32_bf16(ch[ct], rl1, a1, 0, 0, 0);
        a1 = __builtin_amdgcn_mfma_f32_16x16x32_bf16(cl[ct], rh1, a1, 0, 0, 0);

        float4 v0, v1;
        v0.x = __builtin_amdgcn_rcpf(1.f + __expf(-a0[0]));
        v0.y = __builtin_amdgcn_rcpf(1.f + __expf(-a0[1]));
        v0.z = __builtin_amdgcn_rcpf(1.f + __expf(-a0[2]));
        v0.w = __builtin_amdgcn_rcpf(1.f + __expf(-a0[3]));
        v1.x = __builtin_amdgcn_rcpf(1.f + __expf(-a1[0]));
        v1.y = __builtin_amdgcn_rcpf(1.f + __expf(-a1[1]));
        v1.z = __builtin_amdgcn_rcpf(1.f + __expf(-a1[2]));
        v1.w = __builtin_amdgcn_rcpf(1.f + __expf(-a1[3]));

        int col = ct * 16 + lg * 4;
        *(float4*)&slab[w][lr][col]      = v0;
        *(float4*)&slab[w][16 + lr][col] = v1;
    }

    // wave-private writeout: 2 rows x 512B contiguous per instruction
#pragma unroll
    for (int inst = 0; inst < 16; ++inst) {
        int row = inst * 2 + (l >> 5);
        int f4 = l & 31;
        float4 v = *(const float4*)&slab[w][row][f4 * 4];
        *(float4*)(out + ((size_t)(bi * 128 + w * 32 + row)) * NN + bj * 128 + f4 * 4) = v;
    }
}

// ---------------- launch ----------------

extern "C" void kernel_launch(void* const* d_in, const int* in_sizes, int n_in,
                              void* d_out, int out_size, void* d_ws, size_t ws_size,
                              hipStream_t stream) {
    const float* x    = (const float*)d_in[0];
    const int*   ei   = (const int*)d_in[1];
    const float* W1   = (const float*)d_in[2];
    const float* b1   = (const float*)d_in[3];
    const float* Wmu  = (const float*)d_in[4];
    const float* bmu  = (const float*)d_in[5];
    const float* Wls  = (const float*)d_in[6];
    const float* bls  = (const float*)d_in[7];
    const float* eps  = (const float*)d_in[8];

    int E = in_sizes[1] / 2;
    const int* src = ei;
    const int* dst = ei + E;

    float* ws = (float*)d_ws;
    float* dinv  = ws;                         // NN f32
    int*   cnt   = (int*)(dinv + NN);          // NN
    int*   row   = cnt + NN;                   // NN+16
    int*   cur   = row + NN + 16;              // NN
    int*   csr_s = cur + NN;                   // E
    float* csr_w = (float*)(csr_s + E);        // E
    float* h0    = csr_w + E;                  // NN*FH
    float* h     = h0 + (size_t)NN * FH;       // NN*FH
    float* tmu   = h  + (size_t)NN * FH;       // NN*FO
    float* tls   = tmu + (size_t)NN * FO;      // NN*FO
    unsigned short* zh = (unsigned short*)(tls + (size_t)NN * FO);  // NN*FO u16
    unsigned short* zl = zh + (size_t)NN * FO;                      // NN*FO u16

    float* adj    = (float*)d_out;
    float* mu_out = adj + (size_t)NN * NN;
    float* ls_out = mu_out + (size_t)NN * FO;

    k_zero<<<NN / 256, 256, 0, stream>>>(cnt);
    k_count<<<(E + 255) / 256, 256, 0, stream>>>(dst, cnt, E);
    k_scan<<<1, 256, 0, stream>>>(cnt, row);
    k_dinv<<<NN / 256, 256, 0, stream>>>(cnt, dinv, cur);
    k_fill<<<(E + 255) / 256, 256, 0, stream>>>(src, dst, row, cur, dinv, csr_s, csr_w, E);
    k_h0<<<NN / 4, 256, 0, stream>>>(x, W1, h0);
    k_prop1g<<<NN * FH / 256, 256, 0, stream>>>(row, csr_s, csr_w, dinv, h0, b1, h);
    k_t<<<NN / 4, 256, 0, stream>>>(h, Wmu, Wls, tmu, tls);
    k_prop2g<<<NN * FH / 256, 256, 0, stream>>>(row, csr_s, csr_w, dinv, tmu, tls,
                                                bmu, bls, eps, mu_out, ls_out, zh, zl);
    k_decode<<<(NN / 128) * (NN / 128), 256, 0, stream>>>(zh, zl, adj);
}

// Round 12
// 329.512 us; speedup vs baseline: 1.4515x; 1.0198x over previous
//
#include <hip/hip_runtime.h>

#define NN 16384
#define FIN 128
#define FH 64
#define FO 32

typedef __attribute__((ext_vector_type(8))) short bf16x8;
typedef __attribute__((ext_vector_type(4))) float f32x4;

__device__ inline unsigned short f2bf(float f) {          // round-to-nearest-even
    unsigned int u = __float_as_uint(f);
    unsigned int r = (u + 0x7FFFu + ((u >> 16) & 1u)) >> 16;
    return (unsigned short)r;
}
__device__ inline float bf2f(unsigned short b) {
    return __uint_as_float((unsigned int)b << 16);
}

// ---------------- CSR build ----------------

__global__ void k_zero(int* __restrict__ cnt) {
    int i = blockIdx.x * 256 + threadIdx.x;
    cnt[i] = 0;
}

__global__ void k_count(const int* __restrict__ dst, int* __restrict__ cnt, int E) {
    int e = blockIdx.x * 256 + threadIdx.x;
    if (e < E) atomicAdd(&cnt[dst[e] & (NN - 1)], 1);
}

__global__ __launch_bounds__(256) void k_scan(const int* __restrict__ cnt,
                                              int* __restrict__ row) {
    __shared__ int part[256];
    __shared__ int off[257];
    int t = threadIdx.x;
    int base = t * 64;
    int s = 0;
    for (int i = 0; i < 64; ++i) s += cnt[base + i];
    part[t] = s;
    __syncthreads();
    if (t == 0) {
        int a = 0;
        for (int i = 0; i < 256; ++i) { off[i] = a; a += part[i]; }
        off[256] = a;
    }
    __syncthreads();
    int a = off[t];
    for (int i = 0; i < 64; ++i) { row[base + i] = a; a += cnt[base + i]; }
    if (t == 0) row[NN] = off[256];
}

__global__ void k_dinv(const int* __restrict__ cnt, float* __restrict__ dinv,
                       int* __restrict__ cur) {
    int i = blockIdx.x * 256 + threadIdx.x;
    dinv[i] = rsqrtf((float)cnt[i] + 1.0f);
    cur[i] = 0;
}

__global__ void k_fill(const int* __restrict__ src, const int* __restrict__ dst,
                       const int* __restrict__ row, int* __restrict__ cur,
                       const float* __restrict__ dinv,
                       int* __restrict__ csr_s, float* __restrict__ csr_w, int E) {
    int e = blockIdx.x * 256 + threadIdx.x;
    if (e >= E) return;
    int s = src[e] & (NN - 1), d = dst[e] & (NN - 1);
    int pos = atomicAdd(&cur[d], 1);
    int slot = row[d] + pos;
    csr_s[slot] = s;
    csr_w[slot] = dinv[s] * dinv[d];
}

// ---------------- dense transforms ----------------

__global__ void k_h0(const float* __restrict__ x, const float* __restrict__ W1,
                     float* __restrict__ h0) {
    int row = blockIdx.x * 4 + (threadIdx.x >> 6);
    int col = threadIdx.x & 63;
    const float* xr = x + row * FIN;
    float acc = 0.f;
#pragma unroll 8
    for (int k = 0; k < FIN; ++k)
        acc = fmaf(xr[k], W1[k * FH + col], acc);
    h0[row * FH + col] = acc;
}

__global__ void k_t(const float* __restrict__ h, const float* __restrict__ Wmu,
                    const float* __restrict__ Wls, float* __restrict__ tmu,
                    float* __restrict__ tls) {
    int row = blockIdx.x * 4 + (threadIdx.x >> 6);
    int l = threadIdx.x & 63;
    const float* hr = h + row * FH;
    const float* W = (l < 32) ? Wmu : Wls;
    int c = l & 31;
    float acc = 0.f;
#pragma unroll 8
    for (int k = 0; k < FH; ++k)
        acc = fmaf(hr[k], W[k * FO + c], acc);
    if (l < 32) tmu[row * FO + c] = acc;
    else        tls[row * FO + c] = acc;
}

// ---------------- gather propagates ----------------

__global__ void k_prop1g(const int* __restrict__ row, const int* __restrict__ csr_s,
                         const float* __restrict__ csr_w, const float* __restrict__ dinv,
                         const float* __restrict__ h0, const float* __restrict__ b1,
                         float* __restrict__ h) {
    int t = blockIdx.x * 256 + threadIdx.x;
    int i = t >> 6, l = t & 63;
    int beg = row[i], end = row[i + 1];
    float di = dinv[i];
    float acc = di * di * h0[i * FH + l];
    for (int j = beg; j < end; ++j) {
        int s = csr_s[j];
        float w = csr_w[j];
        acc = fmaf(w, h0[s * FH + l], acc);
    }
    float v = acc + b1[l];
    h[i * FH + l] = v > 0.f ? v : 0.f;
}

// layer-2 propagate + reparameterize + bf16 hi/lo split of z
__global__ void k_prop2g(const int* __restrict__ row, const int* __restrict__ csr_s,
                         const float* __restrict__ csr_w, const float* __restrict__ dinv,
                         const float* __restrict__ tmu, const float* __restrict__ tls,
                         const float* __restrict__ bmu, const float* __restrict__ bls,
                         const float* __restrict__ eps,
                         float* __restrict__ mu_out, float* __restrict__ ls_out,
                         unsigned short* __restrict__ zh, unsigned short* __restrict__ zl) {
    int t = blockIdx.x * 256 + threadIdx.x;
    int i = t >> 6, l = t & 63;
    int c = l & 31;
    int beg = row[i], end = row[i + 1];
    const float* tp = (l < 32) ? tmu : tls;
    float di = dinv[i];
    float acc = di * di * tp[i * FO + c];
    for (int j = beg; j < end; ++j) {
        int s = csr_s[j];
        float w = csr_w[j];
        acc = fmaf(w, tp[s * FO + c], acc);
    }
    float v = acc + ((l < 32) ? bmu[c] : bls[c]);
    if (l < 32) mu_out[i * FO + c] = v;
    else        ls_out[i * FO + c] = v;
    float other = __shfl_xor(v, 32);   // lane<32 gets ls
    if (l < 32) {
        float zf = fmaf(eps[i * FO + c], __expf(other), v);
        unsigned short hb = f2bf(zf);
        zh[i * FO + c] = hb;
        zl[i * FO + c] = f2bf(zf - bf2f(hb));
    }
}

// ---------------- decode: adj = sigmoid(z @ z^T) ----------------
// Round-10 structure (MFMA + per-wave LDS slab, no barriers, bj-fast order)
// + NON-TEMPORAL final stores: bypass L2 dirty-allocation so the 1GB write
// stream drains directly (the harness fill kernel achieves 6.5 TB/s this way;
// regular stores measured ~3.6 TB/s).
__global__ __launch_bounds__(256) void k_decode(const unsigned short* __restrict__ zh,
                                                const unsigned short* __restrict__ zl,
                                                float* __restrict__ out) {
    __shared__ float slab[4][32][132];   // per-wave private; 67.6 KB -> 2 blocks/CU
    int bj = blockIdx.x & 127, bi = blockIdx.x >> 7;   // bj fast
    int w = threadIdx.x >> 6;
    int l = threadIdx.x & 63;
    int lr = l & 15, lg = l >> 4;

    auto ld = [&](const unsigned short* p, int t) -> bf16x8 {
        return *(const bf16x8*)(p + ((size_t)t * 16 + lr) * FO + lg * 8);
    };

    int rt = bi * 8 + w * 2;
    bf16x8 rh0 = ld(zh, rt + 0), rl0 = ld(zl, rt + 0);
    bf16x8 rh1 = ld(zh, rt + 1), rl1 = ld(zl, rt + 1);

    bf16x8 ch[8], cl[8];
#pragma unroll
    for (int ct = 0; ct < 8; ++ct) {
        ch[ct] = ld(zh, bj * 8 + ct);
        cl[ct] = ld(zl, bj * 8 + ct);
    }

#pragma unroll
    for (int ct = 0; ct < 8; ++ct) {
        f32x4 a0 = {0.f, 0.f, 0.f, 0.f};
        f32x4 a1 = {0.f, 0.f, 0.f, 0.f};
        a0 = __builtin_amdgcn_mfma_f32_16x16x32_bf16(ch[ct], rh0, a0, 0, 0, 0);
        a0 = __builtin_amdgcn_mfma_f32_16x16x32_bf16(ch[ct], rl0, a0, 0, 0, 0);
        a0 = __builtin_amdgcn_mfma_f32_16x16x32_bf16(cl[ct], rh0, a0, 0, 0, 0);
        a1 = __builtin_amdgcn_mfma_f32_16x16x32_bf16(ch[ct], rh1, a1, 0, 0, 0);
        a1 = __builtin_amdgcn_mfma_f32_16x16x32_bf16(ch[ct], rl1, a1, 0, 0, 0);
        a1 = __builtin_amdgcn_mfma_f32_16x16x32_bf16(cl[ct], rh1, a1, 0, 0, 0);

        float4 v0, v1;
        v0.x = __builtin_amdgcn_rcpf(1.f + __expf(-a0[0]));
        v0.y = __builtin_amdgcn_rcpf(1.f + __expf(-a0[1]));
        v0.z = __builtin_amdgcn_rcpf(1.f + __expf(-a0[2]));
        v0.w = __builtin_amdgcn_rcpf(1.f + __expf(-a0[3]));
        v1.x = __builtin_amdgcn_rcpf(1.f + __expf(-a1[0]));
        v1.y = __builtin_amdgcn_rcpf(1.f + __expf(-a1[1]));
        v1.z = __builtin_amdgcn_rcpf(1.f + __expf(-a1[2]));
        v1.w = __builtin_amdgcn_rcpf(1.f + __expf(-a1[3]));

        int col = ct * 16 + lg * 4;
        *(float4*)&slab[w][lr][col]      = v0;
        *(float4*)&slab[w][16 + lr][col] = v1;
    }

    // wave-private writeout: 2 rows x 512B contiguous per instruction,
    // NON-TEMPORAL (bypass L2 allocation)
#pragma unroll
    for (int inst = 0; inst < 16; ++inst) {
        int row = inst * 2 + (l >> 5);
        int f4 = l & 31;
        f32x4 v = *(const f32x4*)&slab[w][row][f4 * 4];
        f32x4* dst = (f32x4*)(out + ((size_t)(bi * 128 + w * 32 + row)) * NN
                              + bj * 128 + f4 * 4);
        __builtin_nontemporal_store(v, dst);
    }
}

// ---------------- launch ----------------

extern "C" void kernel_launch(void* const* d_in, const int* in_sizes, int n_in,
                              void* d_out, int out_size, void* d_ws, size_t ws_size,
                              hipStream_t stream) {
    const float* x    = (const float*)d_in[0];
    const int*   ei   = (const int*)d_in[1];
    const float* W1   = (const float*)d_in[2];
    const float* b1   = (const float*)d_in[3];
    const float* Wmu  = (const float*)d_in[4];
    const float* bmu  = (const float*)d_in[5];
    const float* Wls  = (const float*)d_in[6];
    const float* bls  = (const float*)d_in[7];
    const float* eps  = (const float*)d_in[8];

    int E = in_sizes[1] / 2;
    const int* src = ei;
    const int* dst = ei + E;

    float* ws = (float*)d_ws;
    float* dinv  = ws;                         // NN f32
    int*   cnt   = (int*)(dinv + NN);          // NN
    int*   row   = cnt + NN;                   // NN+16
    int*   cur   = row + NN + 16;              // NN
    int*   csr_s = cur + NN;                   // E
    float* csr_w = (float*)(csr_s + E);        // E
    float* h0    = csr_w + E;                  // NN*FH
    float* h     = h0 + (size_t)NN * FH;       // NN*FH
    float* tmu   = h  + (size_t)NN * FH;       // NN*FO
    float* tls   = tmu + (size_t)NN * FO;      // NN*FO
    unsigned short* zh = (unsigned short*)(tls + (size_t)NN * FO);  // NN*FO u16
    unsigned short* zl = zh + (size_t)NN * FO;                      // NN*FO u16

    float* adj    = (float*)d_out;
    float* mu_out = adj + (size_t)NN * NN;
    float* ls_out = mu_out + (size_t)NN * FO;

    k_zero<<<NN / 256, 256, 0, stream>>>(cnt);
    k_count<<<(E + 255) / 256, 256, 0, stream>>>(dst, cnt, E);
    k_scan<<<1, 256, 0, stream>>>(cnt, row);
    k_dinv<<<NN / 256, 256, 0, stream>>>(cnt, dinv, cur);
    k_fill<<<(E + 255) / 256, 256, 0, stream>>>(src, dst, row, cur, dinv, csr_s, csr_w, E);
    k_h0<<<NN / 4, 256, 0, stream>>>(x, W1, h0);
    k_prop1g<<<NN * FH / 256, 256, 0, stream>>>(row, csr_s, csr_w, dinv, h0, b1, h);
    k_t<<<NN / 4, 256, 0, stream>>>(h, Wmu, Wls, tmu, tls);
    k_prop2g<<<NN * FH / 256, 256, 0, stream>>>(row, csr_s, csr_w, dinv, tmu, tls,
                                                bmu, bls, eps, mu_out, ls_out, zh, zl);
    k_decode<<<(NN / 128) * (NN / 128), 256, 0, stream>>>(zh, zl, adj);
}